// Round 16
// baseline (290.570 us; speedup 1.0000x reference)
//
#include <hip/hip_runtime.h>
#include <stdint.h>

// ---------- types ----------
typedef __attribute__((ext_vector_type(8))) short  short8;   // 8 bf16 (4 VGPRs)
typedef __attribute__((ext_vector_type(4))) float  f32x4;
typedef __attribute__((ext_vector_type(4))) float  float4v;
typedef __attribute__((ext_vector_type(4))) unsigned short ushort4v;
typedef __attribute__((ext_vector_type(4))) unsigned int   u32x4;

#define DEV __device__ __forceinline__

// ---------- bf16 helpers (RNE) ----------
DEV unsigned short f2bf(float f) {
    union { float f; unsigned int u; } x; x.f = f;
    unsigned int u = x.u;
    unsigned int r = (u + 0x7fffu + ((u >> 16) & 1u)) >> 16;
    return (unsigned short)r;
}
DEV float bf2f(unsigned short b) {
    union { unsigned int u; float f; } x; x.u = ((unsigned int)b) << 16;
    return x.f;
}

// ---------- async global->LDS, 16B/lane ----------
DEV void gll16(const void* g, void* l) {
    __builtin_amdgcn_global_load_lds(
        (const __attribute__((address_space(1))) void*)g,
        (__attribute__((address_space(3))) void*)l, 16, 0, 0);
}

// ---------- problem constants ----------
#define MROWS 4096
#define KDIM  2048
#define NQK   4096

// ============================================================
// prep mega-kernel: casts (xe, v) + 4 weight transpose-casts
// ============================================================
__global__ void prep_kernel(
    const float* __restrict__ xeps, const float* __restrict__ v_in,
    const float* __restrict__ Wea, const float* __restrict__ Wa,
    const float* __restrict__ Wp,  const float* __restrict__ Wep,
    unsigned short* __restrict__ xe16, unsigned short* __restrict__ v16,
    unsigned short* __restrict__ WeaT, unsigned short* __restrict__ WaT,
    unsigned short* __restrict__ WpT,  unsigned short* __restrict__ WepT) {

    __shared__ float tile[32][33];
    const int blk = blockIdx.x, tid = threadIdx.x;

    if (blk < 16384) {   // casts
        const float* in = (blk < 8192) ? xeps : v_in;
        unsigned short* out = (blk < 8192) ? xe16 : v16;
        int i = (blk & 8191) * 256 + tid;
        float4v f = ((const float4v*)in)[i];
        ushort4v o;
        o[0] = f2bf(f[0]); o[1] = f2bf(f[1]); o[2] = f2bf(f[2]); o[3] = f2bf(f[3]);
        ((ushort4v*)out)[i] = o;
        return;
    }
    // transposes
    const float* W; unsigned short* Wt; int K, N, local;
    if (blk < 24576)      { W = Wea; Wt = WeaT; K = KDIM; N = NQK;  local = blk - 16384; }
    else if (blk < 28672) { W = Wa;  Wt = WaT;  K = KDIM; N = KDIM; local = blk - 24576; }
    else if (blk < 32768) { W = Wp;  Wt = WpT;  K = KDIM; N = KDIM; local = blk - 28672; }
    else                  { W = Wep; Wt = WepT; K = KDIM; N = KDIM; local = blk - 32768; }
    const int ntiles = N >> 5;
    const int n0 = (local % ntiles) * 32, k0 = (local / ntiles) * 32;
    const int tx = tid & 31, ty = tid >> 5;
#pragma unroll
    for (int j = 0; j < 32; j += 8)
        tile[ty + j][tx] = W[(size_t)(k0 + ty + j) * N + n0 + tx];
    __syncthreads();
#pragma unroll
    for (int j = 0; j < 32; j += 8)
        Wt[(size_t)(n0 + ty + j) * K + k0 + tx] = f2bf(tile[tx][ty + j]);
}

// ============================================================
// 256x256-tile GEMM, r6/r8 8-phase schedule; TRIPLE descriptor:
// qk(256) + vp(128) + eps(128) in one 512-block launch.
// mode: 0 = plain f32, 1 = fused RoPE (bf16), 2 = transposed vpT.
// ============================================================
__global__ __launch_bounds__(512, 2) void gemm256(
    const unsigned short* __restrict__ A0g, const unsigned short* __restrict__ B0g,
    float* __restrict__ Cf0, unsigned short* __restrict__ Ch0,
    int N0, int tx0, int outbf0, int mode0, int nb0,
    const unsigned short* __restrict__ A1g, const unsigned short* __restrict__ B1g,
    float* __restrict__ Cf1, unsigned short* __restrict__ Ch1,
    int N1, int tx1, int outbf1, int mode1, int nb1,
    const unsigned short* __restrict__ A2g, const unsigned short* __restrict__ B2g,
    float* __restrict__ Cf2, unsigned short* __restrict__ Ch2,
    int N2, int tx2, int outbf2, int mode2,
    int Kst, int Kl,
    const float* __restrict__ rC, const float* __restrict__ rS) {

    __shared__ __align__(16) char lds[131072];

    int blk = blockIdx.x;
    const unsigned short* Ag; const unsigned short* Bg;
    float* Cf; unsigned short* Ch; int N, tx, outbf, nwg, mode;
    if (blk < nb0) {
        Ag = A0g; Bg = B0g; Cf = Cf0; Ch = Ch0; N = N0; tx = tx0;
        outbf = outbf0; mode = mode0; nwg = nb0;
    } else if (blk < nb0 + nb1) {
        blk -= nb0;
        Ag = A1g; Bg = B1g; Cf = Cf1; Ch = Ch1; N = N1; tx = tx1;
        outbf = outbf1; mode = mode1; nwg = nb1;
    } else {
        blk -= nb0 + nb1;
        Ag = A2g; Bg = B2g; Cf = Cf2; Ch = Ch2; N = N2; tx = tx2;
        outbf = outbf2; mode = mode2; nwg = gridDim.x - nb0 - nb1;
    }
    // T1: XCD chunk swizzle (bijective; nwg % 8 == 0)
    { int cpx = nwg >> 3; blk = (blk & 7) * cpx + (blk >> 3); }
    const int bx = blk % tx, by = blk / tx;

    const int tid = threadIdx.x;
    const int lane = tid & 63;
    const int w  = tid >> 6;
    const int lr = lane & 15, lk = lane >> 4;
    const int wm = w >> 2, wn = w & 3;
    const int cswz16 = (lk ^ ((lr >> 3) << 1)) * 16;
    const int rdOff  = lr * 64 + cswz16;
    const int bRow0B = (wn & 1) * 4096;

    const unsigned short* Arow = Ag + (size_t)(by * 256) * Kst;
    const unsigned short* Brow = Bg + (size_t)(bx * 256) * Kst;

    const int srow = tid >> 2;
    const int sclog = (tid & 3) ^ (((tid >> 5) & 1) << 1);
    const unsigned short* aSt0 = Arow + (size_t)srow * Kst + sclog * 8;
    const unsigned short* aSt1 = aSt0 + (size_t)128 * Kst;
    const unsigned short* bSt0 = Brow + (size_t)srow * Kst + sclog * 8;
    const unsigned short* bSt1 = bSt0 + (size_t)128 * Kst;

    char* sA0 = lds;            char* sB0 = lds + 32768;
    char* sA1 = lds + 65536;    char* sB1 = lds + 98304;
    const int sOff = tid * 16;

    const char* aB0 = lds + wm * 16384;
    const char* aB1 = aB0 + 65536;
    const char* bB0 = lds + 32768 + (wn >> 1) * 16384;
    const char* bB1 = bB0 + 65536;

    f32x4 acc[8][4];
#pragma unroll
    for (int m = 0; m < 8; ++m)
#pragma unroll
        for (int n = 0; n < 4; ++n) acc[m][n] = (f32x4){0.f, 0.f, 0.f, 0.f};

    const int NT = Kl >> 6;   // even

    auto STAGE = [&](const unsigned short* srcHalf, int k0, char* ldsHalf) {
        gll16(srcHalf + k0,      ldsHalf + sOff);
        gll16(srcHalf + k0 + 32, ldsHalf + 8192 + sOff);
    };

    // ---- prologue: tile0 full (8) + A(1)h0 (2) ----
    STAGE(aSt0, 0, sA0);  STAGE(aSt1, 0, sA0 + 16384);
    STAGE(bSt0, 0, sB0);  STAGE(bSt1, 0, sB0 + 16384);
    STAGE(aSt0, 64, sA1);
    asm volatile("s_waitcnt vmcnt(2)" ::: "memory");
    __builtin_amdgcn_s_barrier();

#define MFMA_BF(a, b, c) __builtin_amdgcn_mfma_f32_16x16x32_bf16(a, b, c, 0, 0, 0)

#define RD_A(BASE, MH)                                                               \
    _Pragma("unroll") for (int i = 0; i < 4; ++i) {                                  \
        Ar[i][0] = *(const short8*)((BASE) +        (MH) * 4096 + i * 1024 + rdOff); \
        Ar[i][1] = *(const short8*)((BASE) + 8192 + (MH) * 4096 + i * 1024 + rdOff); \
    }

#define RD_B(BASE, NH)                                                                        \
    _Pragma("unroll") for (int j = 0; j < 2; ++j) {                                           \
        Br[j][0] = *(const short8*)((BASE) +        bRow0B + ((NH) * 2 + j) * 1024 + rdOff);  \
        Br[j][1] = *(const short8*)((BASE) + 8192 + bRow0B + ((NH) * 2 + j) * 1024 + rdOff);  \
    }

#define MFMA16(MH, NH)                                                       \
    __builtin_amdgcn_s_setprio(1);                                           \
    _Pragma("unroll") for (int ks = 0; ks < 2; ++ks)                         \
        _Pragma("unroll") for (int i = 0; i < 4; ++i)                        \
            _Pragma("unroll") for (int j = 0; j < 2; ++j)                    \
                acc[(MH) * 4 + i][(NH) * 2 + j] =                            \
                    MFMA_BF(Ar[i][ks], Br[j][ks], acc[(MH) * 4 + i][(NH) * 2 + j]); \
    __builtin_amdgcn_s_setprio(0);

#define PH(RDS, STG, MFMAQ, VMW)                               \
    {                                                          \
        RDS;                                                   \
        STG;                                                   \
        __builtin_amdgcn_s_barrier();                          \
        asm volatile("s_waitcnt lgkmcnt(0)" ::: "memory");     \
        __builtin_amdgcn_sched_barrier(0);                     \
        MFMAQ;                                                 \
        VMW;                                                   \
        __builtin_amdgcn_s_barrier();                          \
    }

#define VMC2 asm volatile("s_waitcnt vmcnt(2)" ::: "memory")

    short8 Ar[4][2], Br[2][2];

    for (int i2 = 0; i2 < NT; i2 += 2) {
        const int kt1 = (i2 + 1) * 64;
        const int kA  = (i2 + 2 < NT ? i2 + 2 : NT - 1) * 64;
        const int kA3 = (i2 + 3 < NT ? i2 + 3 : NT - 1) * 64;

        // ---- K-tile t0 (buf0) ----
        PH({ RD_A(aB0, 0) RD_B(bB0, 0) },
           { STAGE(aSt1, kt1, sA1 + 16384); STAGE(bSt0, kt1, sB1); STAGE(bSt1, kt1, sB1 + 16384); },
           MFMA16(0, 0), {})
        PH({ RD_B(bB0, 1) }, {}, MFMA16(0, 1), {})
        PH({ RD_A(aB0, 1) RD_B(bB0, 0) }, {}, MFMA16(1, 0), {})
        PH({ RD_B(bB0, 1) },
           { STAGE(aSt0, kA, sA0); },
           MFMA16(1, 1), VMC2)

        // ---- K-tile t1 (buf1) ----
        PH({ RD_A(aB1, 0) RD_B(bB1, 0) },
           { STAGE(aSt1, kA, sA0 + 16384); STAGE(bSt0, kA, sB0); STAGE(bSt1, kA, sB0 + 16384); },
           MFMA16(0, 0), {})
        PH({ RD_B(bB1, 1) }, {}, MFMA16(0, 1), {})
        PH({ RD_A(aB1, 1) RD_B(bB1, 0) }, {}, MFMA16(1, 0), {})
        PH({ RD_B(bB1, 1) },
           { STAGE(aSt0, kA3, sA1); },
           MFMA16(1, 1), VMC2)
    }
    asm volatile("s_waitcnt vmcnt(0)" ::: "memory");
#undef RD_A
#undef RD_B
#undef MFMA16
#undef PH
#undef VMC2

    // ---- epilogue: C/D layout col = lane&15, row = (lane>>4)*4 + reg ----
    if (outbf) {
        if (mode == 1) {
#pragma unroll
            for (int mf = 0; mf < 8; ++mf)
#pragma unroll
                for (int nf = 0; nf < 4; ++nf)
#pragma unroll
                    for (int r = 0; r < 4; ++r) {
                        int row = by * 256 + wm * 128 + mf * 16 + lk * 4 + r;
                        int col = bx * 256 + wn * 64 + nf * 16 + lr;
                        float val = acc[mf][nf][r];
                        float part = __shfl_xor(val, 1);
                        int t = row & 1023;
                        int i = (col & 127) >> 1;
                        float c = rC[t * 64 + i];
                        float s = rS[t * 64 + i];
                        float o = (lr & 1) ? (part * s + val * c)
                                           : (val * c - part * s);
                        Ch[(size_t)row * N + col] = f2bf(o);
                    }
        } else if (mode == 2) {
            // transposed vpT write: one 8B store per (mf,nf)
#pragma unroll
            for (int mf = 0; mf < 8; ++mf)
#pragma unroll
                for (int nf = 0; nf < 4; ++nf) {
                    int row0 = by * 256 + wm * 128 + mf * 16 + lk * 4;   // r = 0
                    int col  = bx * 256 + wn * 64 + nf * 16 + lr;
                    int b = row0 >> 10, t0 = row0 & 1023;
                    int h = col >> 7,  d  = col & 127;
                    ushort4v o;
#pragma unroll
                    for (int r = 0; r < 4; ++r) o[r] = f2bf(acc[mf][nf][r]);
                    *(ushort4v*)(Ch + (size_t)(b * 16 + h) * 131072
                                    + (size_t)d * 1024 + t0) = o;
                }
        } else {
#pragma unroll
            for (int mf = 0; mf < 8; ++mf)
#pragma unroll
                for (int nf = 0; nf < 4; ++nf)
#pragma unroll
                    for (int r = 0; r < 4; ++r) {
                        int row = by * 256 + wm * 128 + mf * 16 + lk * 4 + r;
                        int col = bx * 256 + wn * 64 + nf * 16 + lr;
                        Ch[(size_t)row * N + col] = f2bf(acc[mf][nf][r]);
                    }
        }
    } else {
#pragma unroll
        for (int mf = 0; mf < 8; ++mf)
#pragma unroll
            for (int nf = 0; nf < 4; ++nf)
#pragma unroll
                for (int r = 0; r < 4; ++r) {
                    int row = by * 256 + wm * 128 + mf * 16 + lk * 4 + r;
                    int col = bx * 256 + wn * 64 + nf * 16 + lr;
                    Cf[(size_t)row * N + col] = acc[mf][nf][r];
                }
    }
}

// ============================================================
// 128x256-tile GEMM (proj): 32x8 = 256 blocks, no K-split/add.
// ============================================================
__global__ __launch_bounds__(512) void gemm128(
    const unsigned short* __restrict__ Ag, const unsigned short* __restrict__ Bg,
    float* __restrict__ Cf, int N, int tx, int Kst) {

    __shared__ __align__(16) char lds[98304];

    int blk = blockIdx.x;
    { int cpx = (int)gridDim.x >> 3; blk = (blk & 7) * cpx + (blk >> 3); }   // T1
    const int bx = blk % tx, by = blk / tx;

    const int tid = threadIdx.x;
    const int lane = tid & 63;
    const int w  = tid >> 6;
    const int lr = lane & 15, lk = lane >> 4;
    const int wm = w >> 2, wn = w & 3;
    const int cswz16 = (lk ^ ((lr >> 3) << 1)) * 16;
    const int rdOff  = lr * 64 + cswz16;
    const int bRow0B = (wn & 1) * 4096;

    const unsigned short* Arow = Ag + (size_t)(by * 128) * Kst;
    const unsigned short* Brow = Bg + (size_t)(bx * 256) * Kst;

    const int srow = tid >> 2;
    const int sclog = (tid & 3) ^ (((tid >> 5) & 1) << 1);
    const unsigned short* aSt  = Arow + (size_t)srow * Kst + sclog * 8;
    const unsigned short* bSt0 = Brow + (size_t)srow * Kst + sclog * 8;
    const unsigned short* bSt1 = bSt0 + (size_t)128 * Kst;

    const int sOff = tid * 16;

    f32x4 acc[4][4];
#pragma unroll
    for (int m = 0; m < 4; ++m)
#pragma unroll
        for (int n = 0; n < 4; ++n) acc[m][n] = (f32x4){0.f, 0.f, 0.f, 0.f};

    const int NT = Kst >> 6;

    auto STAGE = [&](const unsigned short* srcHalf, int k0, char* ldsHalf) {
        gll16(srcHalf + k0,      ldsHalf + sOff);
        gll16(srcHalf + k0 + 32, ldsHalf + 8192 + sOff);
    };

#define MFMA_BF(a, b, c) __builtin_amdgcn_mfma_f32_16x16x32_bf16(a, b, c, 0, 0, 0)

    // ---- prologue: A(0), B(0), A(1) ----
    STAGE(aSt,  0,  lds);
    STAGE(bSt0, 0,  lds + 16384);  STAGE(bSt1, 0, lds + 32768);
    STAGE(aSt,  64, lds + 49152);
    asm volatile("s_waitcnt vmcnt(2)" ::: "memory");
    __builtin_amdgcn_s_barrier();

    short8 Ar[4][2], Br[2][2];

    for (int t = 0; t < NT; ++t) {
        const int par = t & 1;
        const char* aW = lds + (par ? 49152 : 0) + wm * 4096;
        const char* bC = lds + (par ? 65536 : 16384) + (wn >> 1) * 16384;
        char* dB = lds + (par ? 16384 : 65536);
        char* dA = lds + (par ? 49152 : 0);
        const int kB  = (t + 1 < NT ? t + 1 : NT - 1) * 64;
        const int kA2 = (t + 2 < NT ? t + 2 : NT - 1) * 64;

        // ---- ph0: read A(all) + B nf0-1 ; stage B(t+1) ----
#pragma unroll
        for (int i = 0; i < 4; ++i) {
            Ar[i][0] = *(const short8*)(aW +        i * 1024 + rdOff);
            Ar[i][1] = *(const short8*)(aW + 8192 + i * 1024 + rdOff);
        }
#pragma unroll
        for (int j = 0; j < 2; ++j) {
            Br[j][0] = *(const short8*)(bC +        bRow0B + j * 1024 + rdOff);
            Br[j][1] = *(const short8*)(bC + 8192 + bRow0B + j * 1024 + rdOff);
        }
        STAGE(bSt0, kB, dB);  STAGE(bSt1, kB, dB + 16384);
        __builtin_amdgcn_s_barrier();
        asm volatile("s_waitcnt lgkmcnt(0)" ::: "memory");
        __builtin_amdgcn_sched_barrier(0);
        __builtin_amdgcn_s_setprio(1);
#pragma unroll
        for (int ks = 0; ks < 2; ++ks)
#pragma unroll
            for (int i = 0; i < 4; ++i)
#pragma unroll
                for (int j = 0; j < 2; ++j)
                    acc[i][j] = MFMA_BF(Ar[i][ks], Br[j][ks], acc[i][j]);
        __builtin_amdgcn_s_setprio(0);
        __builtin_amdgcn_s_barrier();

        // ---- ph1: read B nf2-3 ; stage A(t+2) ----
#pragma unroll
        for (int j = 0; j < 2; ++j) {
            Br[j][0] = *(const short8*)(bC +        bRow0B + (2 + j) * 1024 + rdOff);
            Br[j][1] = *(const short8*)(bC + 8192 + bRow0B + (2 + j) * 1024 + rdOff);
        }
        STAGE(aSt, kA2, dA);
        __builtin_amdgcn_s_barrier();
        asm volatile("s_waitcnt lgkmcnt(0)" ::: "memory");
        __builtin_amdgcn_sched_barrier(0);
        __builtin_amdgcn_s_setprio(1);
#pragma unroll
        for (int ks = 0; ks < 2; ++ks)
#pragma unroll
            for (int i = 0; i < 4; ++i)
#pragma unroll
                for (int j = 0; j < 2; ++j)
                    acc[i][2 + j] = MFMA_BF(Ar[i][ks], Br[j][ks], acc[i][2 + j]);
        __builtin_amdgcn_s_setprio(0);
        asm volatile("s_waitcnt vmcnt(2)" ::: "memory");
        __builtin_amdgcn_s_barrier();
    }
    asm volatile("s_waitcnt vmcnt(0)" ::: "memory");
#undef MFMA_BF

    // ---- epilogue: f32 ----
#pragma unroll
    for (int mf = 0; mf < 4; ++mf)
#pragma unroll
        for (int nf = 0; nf < 4; ++nf)
#pragma unroll
            for (int r = 0; r < 4; ++r) {
                int row = by * 128 + wm * 64 + mf * 16 + lk * 4 + r;
                int col = bx * 256 + wn * 64 + nf * 16 + lr;
                Cf[(size_t)row * N + col] = acc[mf][nf][r];
            }
}

// ============================================================
// Flash-style causal attention:
// T14 async-stage split + T13 defer-max (THR=8).
// Round 16: balanced qt mapping -- dispatch round 1 (y=0..3) gets
// qt {7,6,5,4}, round 2 (y=4..7) gets qt {0,1,2,3}; RR pairing per
// CU becomes (7,0),(6,1),(5,2),(4,3) = 18 units each (was 24 max).
// ============================================================
__global__ __launch_bounds__(256) void attn_kernel(
    const unsigned short* __restrict__ qk,
    const unsigned short* __restrict__ vpT,
    unsigned short* __restrict__ y) {

    const int bh = blockIdx.x;
    const int yy = (int)blockIdx.y;
    const int qt = (yy < 4) ? (7 - yy) : (yy - 4);
    const int b = bh >> 4, h = bh & 15;
    const int qb0 = qt * 128;

    __shared__ __align__(16) unsigned short Kt[64 * 128];
    __shared__ __align__(16) unsigned short Vt[128 * 64];
    __shared__ __align__(16) unsigned short Pl[4 * 32 * 72];

    const int tid = threadIdx.x, w = tid >> 6, lane = tid & 63;
    const int lr = lane & 15, lk = lane >> 4;

    const unsigned short* Qb = qk + (size_t)(b * 1024) * 4096 + h * 128;
    const unsigned short* Kb = Qb + 2048;
    const unsigned short* Vg = vpT + (size_t)bh * 128 * 1024;
    unsigned short* Pw = &Pl[w * 32 * 72];

    short8 qf[2][4];
#pragma unroll
    for (int m = 0; m < 2; ++m) {
        const unsigned short* qrow = Qb + (size_t)(qb0 + w * 32 + m * 16 + lr) * 4096;
#pragma unroll
        for (int db = 0; db < 4; ++db)
            qf[m][db] = *(const short8*)(qrow + db * 32 + lk * 8);
    }

    f32x4 acc[2][8];
#pragma unroll
    for (int m = 0; m < 2; ++m)
#pragma unroll
        for (int n = 0; n < 8; ++n) acc[m][n] = (f32x4){0.f, 0.f, 0.f, 0.f};
    float m_i[2][4], l_i[2][4];
#pragma unroll
    for (int m = 0; m < 2; ++m)
#pragma unroll
        for (int r = 0; r < 4; ++r) { m_i[m][r] = -1e30f; l_i[m][r] = 0.f; }

    const int nkt = 2 * qt + 2;

    // ---- prologue: stage tile 0 via global_load_lds ----
#pragma unroll
    for (int c = 0; c < 4; ++c) {
        int base = w * 4096 + c * 1024;
        int row  = (base >> 8) + (lane >> 4);
        int scol = ((lane & 15) * 16) ^ ((row & 7) << 4);
        gll16(Kb + (size_t)row * 4096 + (scol >> 1), (char*)Kt + base);
        int d    = (base >> 7) + (lane >> 3);
        int svol = ((lane & 7) * 16) ^ ((d & 7) << 4);
        gll16(Vg + (size_t)d * 1024 + (svol >> 1), (char*)Vt + base);
    }
    __syncthreads();

    u32x4 kreg[4], vreg[4];

    for (int kt = 0; kt < nkt; ++kt) {
        const bool pf = (kt + 1 < nkt);
        if (pf) {
            const int ktn = kt + 1;
#pragma unroll
            for (int c = 0; c < 4; ++c) {
                int base = w * 4096 + c * 1024;
                int row  = (base >> 8) + (lane >> 4);
                int scol = ((lane & 15) * 16) ^ ((row & 7) << 4);
                kreg[c] = *(const u32x4*)(Kb + (size_t)(ktn * 64 + row) * 4096 + (scol >> 1));
                int d    = (base >> 7) + (lane >> 3);
                int svol = ((lane & 7) * 16) ^ ((d & 7) << 4);
                vreg[c] = *(const u32x4*)(Vg + (size_t)d * 1024 + ktn * 64 + (svol >> 1));
            }
        }

        // ---- S = Q K^T ----
        f32x4 s[2][4];
#pragma unroll
        for (int m = 0; m < 2; ++m)
#pragma unroll
            for (int n = 0; n < 4; ++n) s[m][n] = (f32x4){0.f, 0.f, 0.f, 0.f};
#pragma unroll
        for (int db = 0; db < 4; ++db)
#pragma unroll
            for (int n = 0; n < 4; ++n) {
                int krow = n * 16 + lr;
                int cb = (db * 64 + lk * 16) ^ ((krow & 7) << 4);
                short8 kf = *(const short8*)((const char*)Kt + krow * 256 + cb);
                s[0][n] = __builtin_amdgcn_mfma_f32_16x16x32_bf16(qf[0][db], kf, s[0][n], 0, 0, 0);
                s[1][n] = __builtin_amdgcn_mfma_f32_16x16x32_bf16(qf[1][db], kf, s[1][n], 0, 0, 0);
            }

        const float sc = 0.08838834764831845f;
        const bool diag = (kt >= 2 * qt);
#pragma unroll
        for (int m = 0; m < 2; ++m)
#pragma unroll
            for (int n = 0; n < 4; ++n)
#pragma unroll
                for (int r = 0; r < 4; ++r) {
                    float v = s[m][n][r] * sc;
                    if (diag) {
                        int q   = qb0 + w * 32 + m * 16 + lk * 4 + r;
                        int key = kt * 64 + n * 16 + lr;
                        if (key > q) v = -1e30f;
                    }
                    s[m][n][r] = v;
                }

        // ---- online softmax with defer-max (T13, THR=8) ----
#pragma unroll
        for (int m = 0; m < 2; ++m) {
            float pm[4];
#pragma unroll
            for (int r = 0; r < 4; ++r)
                pm[r] = fmaxf(fmaxf(s[m][0][r], s[m][1][r]), fmaxf(s[m][2][r], s[m][3][r]));
#pragma unroll
            for (int o = 1; o < 16; o <<= 1)
#pragma unroll
                for (int r = 0; r < 4; ++r)
                    pm[r] = fmaxf(pm[r], __shfl_xor(pm[r], o, 16));

            bool small = true;
#pragma unroll
            for (int r = 0; r < 4; ++r)
                small = small && (pm[r] <= m_i[m][r] + 8.0f);
            if (!__all((int)small)) {
                float resc[4];
#pragma unroll
                for (int r = 0; r < 4; ++r) {
                    float mn = fmaxf(m_i[m][r], pm[r]);
                    resc[r] = __expf(m_i[m][r] - mn);
                    m_i[m][r] = mn;
                    l_i[m][r] *= resc[r];
                }
#pragma unroll
                for (int n = 0; n < 8; ++n)
#pragma unroll
                    for (int r = 0; r < 4; ++r)
                        acc[m][n][r] *= resc[r];
            }

            float rs[4] = {0.f, 0.f, 0.f, 0.f};
#pragma unroll
            for (int n = 0; n < 4; ++n)
#pragma unroll
                for (int r = 0; r < 4; ++r) {
                    float p = __expf(s[m][n][r] - m_i[m][r]);
                    s[m][n][r] = p;
                    rs[r] += p;
                }
#pragma unroll
            for (int o = 1; o < 16; o <<= 1)
#pragma unroll
                for (int r = 0; r < 4; ++r)
                    rs[r] += __shfl_xor(rs[r], o, 16);
#pragma unroll
            for (int r = 0; r < 4; ++r)
                l_i[m][r] += rs[r];

#pragma unroll
            for (int n = 0; n < 4; ++n)
#pragma unroll
                for (int r = 0; r < 4; ++r)
                    Pw[(m * 16 + lk * 4 + r) * 72 + n * 16 + lr] = f2bf(s[m][n][r]);
        }

        // ---- Y += P V ----
#pragma unroll
        for (int ks = 0; ks < 2; ++ks) {
            short8 pf0 = *(const short8*)&Pw[(lr) * 72 + ks * 32 + lk * 8];
            short8 pf1 = *(const short8*)&Pw[(16 + lr) * 72 + ks * 32 + lk * 8];
#pragma unroll
            for (int n8 = 0; n8 < 8; ++n8) {
                int d  = n8 * 16 + lr;
                int cb = (ks * 64 + lk * 16) ^ ((d & 7) << 4);
                short8 vf = *(const short8*)((const char*)Vt + d * 128 + cb);
                acc[0][n8] = __builtin_amdgcn_mfma_f32_16x16x32_bf16(pf0, vf, acc[0][n8], 0, 0, 0);
                acc[1][n8] = __builtin_amdgcn_mfma_f32_16x16x32_bf16(pf1, vf, acc[1][n8], 0, 0, 0);
            }
        }
        __syncthreads();

        if (pf) {
#pragma unroll
            for (int c = 0; c < 4; ++c) {
                int base = w * 4096 + c * 1024;
                *(u32x4*)((char*)Kt + base + lane * 16) = kreg[c];
                *(u32x4*)((char*)Vt + base + lane * 16) = vreg[c];
            }
        }
        __syncthreads();
    }

    unsigned short* yb = y + (size_t)(b * 1024) * 2048 + h * 128;
#pragma unroll
    for (int m = 0; m < 2; ++m)
#pragma unroll
        for (int n8 = 0; n8 < 8; ++n8)
#pragma unroll
            for (int r = 0; r < 4; ++r) {
                int t = qb0 + w * 32 + m * 16 + lk * 4 + r;
                int d = n8 * 16 + lr;
                yb[(size_t)t * 2048 + d] = f2bf(acc[m][n8][r] / l_i[m][r]);
            }
}

// ============================================================
// host launch
// ============================================================
extern "C" void kernel_launch(void* const* d_in, const int* in_sizes, int n_in,
                              void* d_out, int out_size, void* d_ws, size_t ws_size,
                              hipStream_t stream) {
    const float* v_in  = (const float*)d_in[0];
    const float* xeps  = (const float*)d_in[1];
    const float* fcos  = (const float*)d_in[2];
    const float* fsin  = (const float*)d_in[3];
    const float* Wea   = (const float*)d_in[4];
    const float* Wa    = (const float*)d_in[5];
    const float* Wp    = (const float*)d_in[6];
    const float* Wep   = (const float*)d_in[7];
    float* out = (float*)d_out;

    char* ws = (char*)d_ws;
    unsigned short* xe16 = (unsigned short*)ws;  ws += (size_t)MROWS * KDIM * 2;
    unsigned short* v16  = (unsigned short*)ws;  ws += (size_t)MROWS * KDIM * 2;
    unsigned short* WeaT = (unsigned short*)ws;  ws += (size_t)NQK * KDIM * 2;
    unsigned short* WaT  = (unsigned short*)ws;  ws += (size_t)KDIM * KDIM * 2;
    unsigned short* WpT  = (unsigned short*)ws;  ws += (size_t)KDIM * KDIM * 2;
    unsigned short* WepT = (unsigned short*)ws;  ws += (size_t)KDIM * KDIM * 2;
    unsigned short* qk16 = (unsigned short*)ws;  ws += (size_t)MROWS * NQK * 2;
    unsigned short* vpT  = (unsigned short*)ws;  ws += (size_t)MROWS * KDIM * 2;  // [64 bh][128 d][1024 t]
    unsigned short* y16  = (unsigned short*)ws;  ws += (size_t)MROWS * KDIM * 2;

    // 1. prep: casts + all 4 weight transposes, one launch
    prep_kernel<<<36864, 256, 0, stream>>>(xeps, v_in, Wea, Wa, Wp, Wep,
                                           xe16, v16, WeaT, WaT, WpT, WepT);

    // 2. merged: qk (fused RoPE, 256 blk) + vpT (mode 2, 128 blk)
    //            + x_eps_out (f32, 128 blk) = 512 blocks, one launch
    gemm256<<<512, 512, 0, stream>>>(
        xe16, WeaT, nullptr, qk16, NQK, 16, 1, 1, 256,
        v16,  WaT,  nullptr, vpT, KDIM, 8, 1, 2, 128,
        xe16, WepT, out + (size_t)MROWS * KDIM, nullptr, KDIM, 8, 0, 0,
        KDIM, KDIM, fcos, fsin);

    // 3. attention -> y16
    attn_kernel<<<dim3(64, 8), 256, 0, stream>>>(qk16, vpT, y16);

    // 4. v_out = y16 @ WpT : 128x256 tiles, 256 blocks, full K
    gemm128<<<256, 512, 0, stream>>>(y16, WpT, out, KDIM, 8, KDIM);
}

// Round 17
// 278.527 us; speedup vs baseline: 1.0432x; 1.0432x over previous
//
#include <hip/hip_runtime.h>
#include <stdint.h>

// ---------- types ----------
typedef __attribute__((ext_vector_type(8))) short  short8;   // 8 bf16 (4 VGPRs)
typedef __attribute__((ext_vector_type(4))) float  f32x4;
typedef __attribute__((ext_vector_type(4))) float  float4v;
typedef __attribute__((ext_vector_type(4))) unsigned short ushort4v;
typedef __attribute__((ext_vector_type(4))) unsigned int   u32x4;

#define DEV __device__ __forceinline__

// ---------- bf16 helpers (RNE) ----------
DEV unsigned short f2bf(float f) {
    union { float f; unsigned int u; } x; x.f = f;
    unsigned int u = x.u;
    unsigned int r = (u + 0x7fffu + ((u >> 16) & 1u)) >> 16;
    return (unsigned short)r;
}
DEV float bf2f(unsigned short b) {
    union { unsigned int u; float f; } x; x.u = ((unsigned int)b) << 16;
    return x.f;
}

// ---------- async global->LDS, 16B/lane ----------
DEV void gll16(const void* g, void* l) {
    __builtin_amdgcn_global_load_lds(
        (const __attribute__((address_space(1))) void*)g,
        (__attribute__((address_space(3))) void*)l, 16, 0, 0);
}

// ---------- problem constants ----------
#define MROWS 4096
#define KDIM  2048
#define NQK   4096

// ============================================================
// prep mega-kernel: casts (xe, v) + 4 weight transpose-casts
// ============================================================
__global__ void prep_kernel(
    const float* __restrict__ xeps, const float* __restrict__ v_in,
    const float* __restrict__ Wea, const float* __restrict__ Wa,
    const float* __restrict__ Wp,  const float* __restrict__ Wep,
    unsigned short* __restrict__ xe16, unsigned short* __restrict__ v16,
    unsigned short* __restrict__ WeaT, unsigned short* __restrict__ WaT,
    unsigned short* __restrict__ WpT,  unsigned short* __restrict__ WepT) {

    __shared__ float tile[32][33];
    const int blk = blockIdx.x, tid = threadIdx.x;

    if (blk < 16384) {   // casts
        const float* in = (blk < 8192) ? xeps : v_in;
        unsigned short* out = (blk < 8192) ? xe16 : v16;
        int i = (blk & 8191) * 256 + tid;
        float4v f = ((const float4v*)in)[i];
        ushort4v o;
        o[0] = f2bf(f[0]); o[1] = f2bf(f[1]); o[2] = f2bf(f[2]); o[3] = f2bf(f[3]);
        ((ushort4v*)out)[i] = o;
        return;
    }
    // transposes
    const float* W; unsigned short* Wt; int K, N, local;
    if (blk < 24576)      { W = Wea; Wt = WeaT; K = KDIM; N = NQK;  local = blk - 16384; }
    else if (blk < 28672) { W = Wa;  Wt = WaT;  K = KDIM; N = KDIM; local = blk - 24576; }
    else if (blk < 32768) { W = Wp;  Wt = WpT;  K = KDIM; N = KDIM; local = blk - 28672; }
    else                  { W = Wep; Wt = WepT; K = KDIM; N = KDIM; local = blk - 32768; }
    const int ntiles = N >> 5;
    const int n0 = (local % ntiles) * 32, k0 = (local / ntiles) * 32;
    const int tx = tid & 31, ty = tid >> 5;
#pragma unroll
    for (int j = 0; j < 32; j += 8)
        tile[ty + j][tx] = W[(size_t)(k0 + ty + j) * N + n0 + tx];
    __syncthreads();
#pragma unroll
    for (int j = 0; j < 32; j += 8)
        Wt[(size_t)(n0 + ty + j) * K + k0 + tx] = f2bf(tile[tx][ty + j]);
}

// ============================================================
// 256x256-tile GEMM, r6/r8 8-phase schedule; TRIPLE descriptor:
// qk(256) + vp(128) + eps(128) in one 512-block launch.
// mode: 0 = plain f32, 1 = fused RoPE (bf16), 2 = transposed vpT.
// ============================================================
__global__ __launch_bounds__(512, 2) void gemm256(
    const unsigned short* __restrict__ A0g, const unsigned short* __restrict__ B0g,
    float* __restrict__ Cf0, unsigned short* __restrict__ Ch0,
    int N0, int tx0, int outbf0, int mode0, int nb0,
    const unsigned short* __restrict__ A1g, const unsigned short* __restrict__ B1g,
    float* __restrict__ Cf1, unsigned short* __restrict__ Ch1,
    int N1, int tx1, int outbf1, int mode1, int nb1,
    const unsigned short* __restrict__ A2g, const unsigned short* __restrict__ B2g,
    float* __restrict__ Cf2, unsigned short* __restrict__ Ch2,
    int N2, int tx2, int outbf2, int mode2,
    int Kst, int Kl,
    const float* __restrict__ rC, const float* __restrict__ rS) {

    __shared__ __align__(16) char lds[131072];

    int blk = blockIdx.x;
    const unsigned short* Ag; const unsigned short* Bg;
    float* Cf; unsigned short* Ch; int N, tx, outbf, nwg, mode;
    if (blk < nb0) {
        Ag = A0g; Bg = B0g; Cf = Cf0; Ch = Ch0; N = N0; tx = tx0;
        outbf = outbf0; mode = mode0; nwg = nb0;
    } else if (blk < nb0 + nb1) {
        blk -= nb0;
        Ag = A1g; Bg = B1g; Cf = Cf1; Ch = Ch1; N = N1; tx = tx1;
        outbf = outbf1; mode = mode1; nwg = nb1;
    } else {
        blk -= nb0 + nb1;
        Ag = A2g; Bg = B2g; Cf = Cf2; Ch = Ch2; N = N2; tx = tx2;
        outbf = outbf2; mode = mode2; nwg = gridDim.x - nb0 - nb1;
    }
    // T1: XCD chunk swizzle (bijective; nwg % 8 == 0)
    { int cpx = nwg >> 3; blk = (blk & 7) * cpx + (blk >> 3); }
    const int bx = blk % tx, by = blk / tx;

    const int tid = threadIdx.x;
    const int lane = tid & 63;
    const int w  = tid >> 6;
    const int lr = lane & 15, lk = lane >> 4;
    const int wm = w >> 2, wn = w & 3;
    const int cswz16 = (lk ^ ((lr >> 3) << 1)) * 16;
    const int rdOff  = lr * 64 + cswz16;
    const int bRow0B = (wn & 1) * 4096;

    const unsigned short* Arow = Ag + (size_t)(by * 256) * Kst;
    const unsigned short* Brow = Bg + (size_t)(bx * 256) * Kst;

    const int srow = tid >> 2;
    const int sclog = (tid & 3) ^ (((tid >> 5) & 1) << 1);
    const unsigned short* aSt0 = Arow + (size_t)srow * Kst + sclog * 8;
    const unsigned short* aSt1 = aSt0 + (size_t)128 * Kst;
    const unsigned short* bSt0 = Brow + (size_t)srow * Kst + sclog * 8;
    const unsigned short* bSt1 = bSt0 + (size_t)128 * Kst;

    char* sA0 = lds;            char* sB0 = lds + 32768;
    char* sA1 = lds + 65536;    char* sB1 = lds + 98304;
    const int sOff = tid * 16;

    const char* aB0 = lds + wm * 16384;
    const char* aB1 = aB0 + 65536;
    const char* bB0 = lds + 32768 + (wn >> 1) * 16384;
    const char* bB1 = bB0 + 65536;

    f32x4 acc[8][4];
#pragma unroll
    for (int m = 0; m < 8; ++m)
#pragma unroll
        for (int n = 0; n < 4; ++n) acc[m][n] = (f32x4){0.f, 0.f, 0.f, 0.f};

    const int NT = Kl >> 6;   // even

    auto STAGE = [&](const unsigned short* srcHalf, int k0, char* ldsHalf) {
        gll16(srcHalf + k0,      ldsHalf + sOff);
        gll16(srcHalf + k0 + 32, ldsHalf + 8192 + sOff);
    };

    // ---- prologue: tile0 full (8) + A(1)h0 (2) ----
    STAGE(aSt0, 0, sA0);  STAGE(aSt1, 0, sA0 + 16384);
    STAGE(bSt0, 0, sB0);  STAGE(bSt1, 0, sB0 + 16384);
    STAGE(aSt0, 64, sA1);
    asm volatile("s_waitcnt vmcnt(2)" ::: "memory");
    __builtin_amdgcn_s_barrier();

#define MFMA_BF(a, b, c) __builtin_amdgcn_mfma_f32_16x16x32_bf16(a, b, c, 0, 0, 0)

#define RD_A(BASE, MH)                                                               \
    _Pragma("unroll") for (int i = 0; i < 4; ++i) {                                  \
        Ar[i][0] = *(const short8*)((BASE) +        (MH) * 4096 + i * 1024 + rdOff); \
        Ar[i][1] = *(const short8*)((BASE) + 8192 + (MH) * 4096 + i * 1024 + rdOff); \
    }

#define RD_B(BASE, NH)                                                                        \
    _Pragma("unroll") for (int j = 0; j < 2; ++j) {                                           \
        Br[j][0] = *(const short8*)((BASE) +        bRow0B + ((NH) * 2 + j) * 1024 + rdOff);  \
        Br[j][1] = *(const short8*)((BASE) + 8192 + bRow0B + ((NH) * 2 + j) * 1024 + rdOff);  \
    }

#define MFMA16(MH, NH)                                                       \
    __builtin_amdgcn_s_setprio(1);                                           \
    _Pragma("unroll") for (int ks = 0; ks < 2; ++ks)                         \
        _Pragma("unroll") for (int i = 0; i < 4; ++i)                        \
            _Pragma("unroll") for (int j = 0; j < 2; ++j)                    \
                acc[(MH) * 4 + i][(NH) * 2 + j] =                            \
                    MFMA_BF(Ar[i][ks], Br[j][ks], acc[(MH) * 4 + i][(NH) * 2 + j]); \
    __builtin_amdgcn_s_setprio(0);

#define PH(RDS, STG, MFMAQ, VMW)                               \
    {                                                          \
        RDS;                                                   \
        STG;                                                   \
        __builtin_amdgcn_s_barrier();                          \
        asm volatile("s_waitcnt lgkmcnt(0)" ::: "memory");     \
        __builtin_amdgcn_sched_barrier(0);                     \
        MFMAQ;                                                 \
        VMW;                                                   \
        __builtin_amdgcn_s_barrier();                          \
    }

#define VMC2 asm volatile("s_waitcnt vmcnt(2)" ::: "memory")

    short8 Ar[4][2], Br[2][2];

    for (int i2 = 0; i2 < NT; i2 += 2) {
        const int kt1 = (i2 + 1) * 64;
        const int kA  = (i2 + 2 < NT ? i2 + 2 : NT - 1) * 64;
        const int kA3 = (i2 + 3 < NT ? i2 + 3 : NT - 1) * 64;

        // ---- K-tile t0 (buf0) ----
        PH({ RD_A(aB0, 0) RD_B(bB0, 0) },
           { STAGE(aSt1, kt1, sA1 + 16384); STAGE(bSt0, kt1, sB1); STAGE(bSt1, kt1, sB1 + 16384); },
           MFMA16(0, 0), {})
        PH({ RD_B(bB0, 1) }, {}, MFMA16(0, 1), {})
        PH({ RD_A(aB0, 1) RD_B(bB0, 0) }, {}, MFMA16(1, 0), {})
        PH({ RD_B(bB0, 1) },
           { STAGE(aSt0, kA, sA0); },
           MFMA16(1, 1), VMC2)

        // ---- K-tile t1 (buf1) ----
        PH({ RD_A(aB1, 0) RD_B(bB1, 0) },
           { STAGE(aSt1, kA, sA0 + 16384); STAGE(bSt0, kA, sB0); STAGE(bSt1, kA, sB0 + 16384); },
           MFMA16(0, 0), {})
        PH({ RD_B(bB1, 1) }, {}, MFMA16(0, 1), {})
        PH({ RD_A(aB1, 1) RD_B(bB1, 0) }, {}, MFMA16(1, 0), {})
        PH({ RD_B(bB1, 1) },
           { STAGE(aSt0, kA3, sA1); },
           MFMA16(1, 1), VMC2)
    }
    asm volatile("s_waitcnt vmcnt(0)" ::: "memory");
#undef RD_A
#undef RD_B
#undef MFMA16
#undef PH
#undef VMC2

    // ---- epilogue: C/D layout col = lane&15, row = (lane>>4)*4 + reg ----
    if (outbf) {
        if (mode == 1) {
#pragma unroll
            for (int mf = 0; mf < 8; ++mf)
#pragma unroll
                for (int nf = 0; nf < 4; ++nf)
#pragma unroll
                    for (int r = 0; r < 4; ++r) {
                        int row = by * 256 + wm * 128 + mf * 16 + lk * 4 + r;
                        int col = bx * 256 + wn * 64 + nf * 16 + lr;
                        float val = acc[mf][nf][r];
                        float part = __shfl_xor(val, 1);
                        int t = row & 1023;
                        int i = (col & 127) >> 1;
                        float c = rC[t * 64 + i];
                        float s = rS[t * 64 + i];
                        float o = (lr & 1) ? (part * s + val * c)
                                           : (val * c - part * s);
                        Ch[(size_t)row * N + col] = f2bf(o);
                    }
        } else if (mode == 2) {
            // transposed vpT write: one 8B store per (mf,nf)
#pragma unroll
            for (int mf = 0; mf < 8; ++mf)
#pragma unroll
                for (int nf = 0; nf < 4; ++nf) {
                    int row0 = by * 256 + wm * 128 + mf * 16 + lk * 4;   // r = 0
                    int col  = bx * 256 + wn * 64 + nf * 16 + lr;
                    int b = row0 >> 10, t0 = row0 & 1023;
                    int h = col >> 7,  d  = col & 127;
                    ushort4v o;
#pragma unroll
                    for (int r = 0; r < 4; ++r) o[r] = f2bf(acc[mf][nf][r]);
                    *(ushort4v*)(Ch + (size_t)(b * 16 + h) * 131072
                                    + (size_t)d * 1024 + t0) = o;
                }
        } else {
#pragma unroll
            for (int mf = 0; mf < 8; ++mf)
#pragma unroll
                for (int nf = 0; nf < 4; ++nf)
#pragma unroll
                    for (int r = 0; r < 4; ++r) {
                        int row = by * 256 + wm * 128 + mf * 16 + lk * 4 + r;
                        int col = bx * 256 + wn * 64 + nf * 16 + lr;
                        Ch[(size_t)row * N + col] = f2bf(acc[mf][nf][r]);
                    }
        }
    } else {
#pragma unroll
        for (int mf = 0; mf < 8; ++mf)
#pragma unroll
            for (int nf = 0; nf < 4; ++nf)
#pragma unroll
                for (int r = 0; r < 4; ++r) {
                    int row = by * 256 + wm * 128 + mf * 16 + lk * 4 + r;
                    int col = bx * 256 + wn * 64 + nf * 16 + lr;
                    Cf[(size_t)row * N + col] = acc[mf][nf][r];
                }
    }
}

// ============================================================
// 128x256-tile GEMM (proj): 32x8 = 256 blocks, no K-split/add.
// ============================================================
__global__ __launch_bounds__(512) void gemm128(
    const unsigned short* __restrict__ Ag, const unsigned short* __restrict__ Bg,
    float* __restrict__ Cf, int N, int tx, int Kst) {

    __shared__ __align__(16) char lds[98304];

    int blk = blockIdx.x;
    { int cpx = (int)gridDim.x >> 3; blk = (blk & 7) * cpx + (blk >> 3); }   // T1
    const int bx = blk % tx, by = blk / tx;

    const int tid = threadIdx.x;
    const int lane = tid & 63;
    const int w  = tid >> 6;
    const int lr = lane & 15, lk = lane >> 4;
    const int wm = w >> 2, wn = w & 3;
    const int cswz16 = (lk ^ ((lr >> 3) << 1)) * 16;
    const int rdOff  = lr * 64 + cswz16;
    const int bRow0B = (wn & 1) * 4096;

    const unsigned short* Arow = Ag + (size_t)(by * 128) * Kst;
    const unsigned short* Brow = Bg + (size_t)(bx * 256) * Kst;

    const int srow = tid >> 2;
    const int sclog = (tid & 3) ^ (((tid >> 5) & 1) << 1);
    const unsigned short* aSt  = Arow + (size_t)srow * Kst + sclog * 8;
    const unsigned short* bSt0 = Brow + (size_t)srow * Kst + sclog * 8;
    const unsigned short* bSt1 = bSt0 + (size_t)128 * Kst;

    const int sOff = tid * 16;

    f32x4 acc[4][4];
#pragma unroll
    for (int m = 0; m < 4; ++m)
#pragma unroll
        for (int n = 0; n < 4; ++n) acc[m][n] = (f32x4){0.f, 0.f, 0.f, 0.f};

    const int NT = Kst >> 6;

    auto STAGE = [&](const unsigned short* srcHalf, int k0, char* ldsHalf) {
        gll16(srcHalf + k0,      ldsHalf + sOff);
        gll16(srcHalf + k0 + 32, ldsHalf + 8192 + sOff);
    };

#define MFMA_BF(a, b, c) __builtin_amdgcn_mfma_f32_16x16x32_bf16(a, b, c, 0, 0, 0)

    // ---- prologue: A(0), B(0), A(1) ----
    STAGE(aSt,  0,  lds);
    STAGE(bSt0, 0,  lds + 16384);  STAGE(bSt1, 0, lds + 32768);
    STAGE(aSt,  64, lds + 49152);
    asm volatile("s_waitcnt vmcnt(2)" ::: "memory");
    __builtin_amdgcn_s_barrier();

    short8 Ar[4][2], Br[2][2];

    for (int t = 0; t < NT; ++t) {
        const int par = t & 1;
        const char* aW = lds + (par ? 49152 : 0) + wm * 4096;
        const char* bC = lds + (par ? 65536 : 16384) + (wn >> 1) * 16384;
        char* dB = lds + (par ? 16384 : 65536);
        char* dA = lds + (par ? 49152 : 0);
        const int kB  = (t + 1 < NT ? t + 1 : NT - 1) * 64;
        const int kA2 = (t + 2 < NT ? t + 2 : NT - 1) * 64;

        // ---- ph0: read A(all) + B nf0-1 ; stage B(t+1) ----
#pragma unroll
        for (int i = 0; i < 4; ++i) {
            Ar[i][0] = *(const short8*)(aW +        i * 1024 + rdOff);
            Ar[i][1] = *(const short8*)(aW + 8192 + i * 1024 + rdOff);
        }
#pragma unroll
        for (int j = 0; j < 2; ++j) {
            Br[j][0] = *(const short8*)(bC +        bRow0B + j * 1024 + rdOff);
            Br[j][1] = *(const short8*)(bC + 8192 + bRow0B + j * 1024 + rdOff);
        }
        STAGE(bSt0, kB, dB);  STAGE(bSt1, kB, dB + 16384);
        __builtin_amdgcn_s_barrier();
        asm volatile("s_waitcnt lgkmcnt(0)" ::: "memory");
        __builtin_amdgcn_sched_barrier(0);
        __builtin_amdgcn_s_setprio(1);
#pragma unroll
        for (int ks = 0; ks < 2; ++ks)
#pragma unroll
            for (int i = 0; i < 4; ++i)
#pragma unroll
                for (int j = 0; j < 2; ++j)
                    acc[i][j] = MFMA_BF(Ar[i][ks], Br[j][ks], acc[i][j]);
        __builtin_amdgcn_s_setprio(0);
        __builtin_amdgcn_s_barrier();

        // ---- ph1: read B nf2-3 ; stage A(t+2) ----
#pragma unroll
        for (int j = 0; j < 2; ++j) {
            Br[j][0] = *(const short8*)(bC +        bRow0B + (2 + j) * 1024 + rdOff);
            Br[j][1] = *(const short8*)(bC + 8192 + bRow0B + (2 + j) * 1024 + rdOff);
        }
        STAGE(aSt, kA2, dA);
        __builtin_amdgcn_s_barrier();
        asm volatile("s_waitcnt lgkmcnt(0)" ::: "memory");
        __builtin_amdgcn_sched_barrier(0);
        __builtin_amdgcn_s_setprio(1);
#pragma unroll
        for (int ks = 0; ks < 2; ++ks)
#pragma unroll
            for (int i = 0; i < 4; ++i)
#pragma unroll
                for (int j = 0; j < 2; ++j)
                    acc[i][2 + j] = MFMA_BF(Ar[i][ks], Br[j][ks], acc[i][2 + j]);
        __builtin_amdgcn_s_setprio(0);
        asm volatile("s_waitcnt vmcnt(2)" ::: "memory");
        __builtin_amdgcn_s_barrier();
    }
    asm volatile("s_waitcnt vmcnt(0)" ::: "memory");
#undef MFMA_BF

    // ---- epilogue: f32 ----
#pragma unroll
    for (int mf = 0; mf < 4; ++mf)
#pragma unroll
        for (int nf = 0; nf < 4; ++nf)
#pragma unroll
            for (int r = 0; r < 4; ++r) {
                int row = by * 128 + wm * 64 + mf * 16 + lk * 4 + r;
                int col = bx * 256 + wn * 64 + nf * 16 + lr;
                Cf[(size_t)row * N + col] = acc[mf][nf][r];
            }
}

// ============================================================
// Flash-style causal attention:
// T14 async-stage split + T13 defer-max (THR=8).
// qt = 7 - blockIdx.y: heavy tiles dispatch FIRST (LPT order --
// r16 showed ascending second-half order costs +12us).
// ============================================================
__global__ __launch_bounds__(256) void attn_kernel(
    const unsigned short* __restrict__ qk,
    const unsigned short* __restrict__ vpT,
    unsigned short* __restrict__ y) {

    const int bh = blockIdx.x;
    const int qt = 7 - (int)blockIdx.y;
    const int b = bh >> 4, h = bh & 15;
    const int qb0 = qt * 128;

    __shared__ __align__(16) unsigned short Kt[64 * 128];
    __shared__ __align__(16) unsigned short Vt[128 * 64];
    __shared__ __align__(16) unsigned short Pl[4 * 32 * 72];

    const int tid = threadIdx.x, w = tid >> 6, lane = tid & 63;
    const int lr = lane & 15, lk = lane >> 4;

    const unsigned short* Qb = qk + (size_t)(b * 1024) * 4096 + h * 128;
    const unsigned short* Kb = Qb + 2048;
    const unsigned short* Vg = vpT + (size_t)bh * 128 * 1024;
    unsigned short* Pw = &Pl[w * 32 * 72];

    short8 qf[2][4];
#pragma unroll
    for (int m = 0; m < 2; ++m) {
        const unsigned short* qrow = Qb + (size_t)(qb0 + w * 32 + m * 16 + lr) * 4096;
#pragma unroll
        for (int db = 0; db < 4; ++db)
            qf[m][db] = *(const short8*)(qrow + db * 32 + lk * 8);
    }

    f32x4 acc[2][8];
#pragma unroll
    for (int m = 0; m < 2; ++m)
#pragma unroll
        for (int n = 0; n < 8; ++n) acc[m][n] = (f32x4){0.f, 0.f, 0.f, 0.f};
    float m_i[2][4], l_i[2][4];
#pragma unroll
    for (int m = 0; m < 2; ++m)
#pragma unroll
        for (int r = 0; r < 4; ++r) { m_i[m][r] = -1e30f; l_i[m][r] = 0.f; }

    const int nkt = 2 * qt + 2;

    // ---- prologue: stage tile 0 via global_load_lds ----
#pragma unroll
    for (int c = 0; c < 4; ++c) {
        int base = w * 4096 + c * 1024;
        int row  = (base >> 8) + (lane >> 4);
        int scol = ((lane & 15) * 16) ^ ((row & 7) << 4);
        gll16(Kb + (size_t)row * 4096 + (scol >> 1), (char*)Kt + base);
        int d    = (base >> 7) + (lane >> 3);
        int svol = ((lane & 7) * 16) ^ ((d & 7) << 4);
        gll16(Vg + (size_t)d * 1024 + (svol >> 1), (char*)Vt + base);
    }
    __syncthreads();

    u32x4 kreg[4], vreg[4];

    for (int kt = 0; kt < nkt; ++kt) {
        const bool pf = (kt + 1 < nkt);
        if (pf) {
            const int ktn = kt + 1;
#pragma unroll
            for (int c = 0; c < 4; ++c) {
                int base = w * 4096 + c * 1024;
                int row  = (base >> 8) + (lane >> 4);
                int scol = ((lane & 15) * 16) ^ ((row & 7) << 4);
                kreg[c] = *(const u32x4*)(Kb + (size_t)(ktn * 64 + row) * 4096 + (scol >> 1));
                int d    = (base >> 7) + (lane >> 3);
                int svol = ((lane & 7) * 16) ^ ((d & 7) << 4);
                vreg[c] = *(const u32x4*)(Vg + (size_t)d * 1024 + ktn * 64 + (svol >> 1));
            }
        }

        // ---- S = Q K^T ----
        f32x4 s[2][4];
#pragma unroll
        for (int m = 0; m < 2; ++m)
#pragma unroll
            for (int n = 0; n < 4; ++n) s[m][n] = (f32x4){0.f, 0.f, 0.f, 0.f};
#pragma unroll
        for (int db = 0; db < 4; ++db)
#pragma unroll
            for (int n = 0; n < 4; ++n) {
                int krow = n * 16 + lr;
                int cb = (db * 64 + lk * 16) ^ ((krow & 7) << 4);
                short8 kf = *(const short8*)((const char*)Kt + krow * 256 + cb);
                s[0][n] = __builtin_amdgcn_mfma_f32_16x16x32_bf16(qf[0][db], kf, s[0][n], 0, 0, 0);
                s[1][n] = __builtin_amdgcn_mfma_f32_16x16x32_bf16(qf[1][db], kf, s[1][n], 0, 0, 0);
            }

        const float sc = 0.08838834764831845f;
        const bool diag = (kt >= 2 * qt);
#pragma unroll
        for (int m = 0; m < 2; ++m)
#pragma unroll
            for (int n = 0; n < 4; ++n)
#pragma unroll
                for (int r = 0; r < 4; ++r) {
                    float v = s[m][n][r] * sc;
                    if (diag) {
                        int q   = qb0 + w * 32 + m * 16 + lk * 4 + r;
                        int key = kt * 64 + n * 16 + lr;
                        if (key > q) v = -1e30f;
                    }
                    s[m][n][r] = v;
                }

        // ---- online softmax with defer-max (T13, THR=8) ----
#pragma unroll
        for (int m = 0; m < 2; ++m) {
            float pm[4];
#pragma unroll
            for (int r = 0; r < 4; ++r)
                pm[r] = fmaxf(fmaxf(s[m][0][r], s[m][1][r]), fmaxf(s[m][2][r], s[m][3][r]));
#pragma unroll
            for (int o = 1; o < 16; o <<= 1)
#pragma unroll
                for (int r = 0; r < 4; ++r)
                    pm[r] = fmaxf(pm[r], __shfl_xor(pm[r], o, 16));

            bool small = true;
#pragma unroll
            for (int r = 0; r < 4; ++r)
                small = small && (pm[r] <= m_i[m][r] + 8.0f);
            if (!__all((int)small)) {
                float resc[4];
#pragma unroll
                for (int r = 0; r < 4; ++r) {
                    float mn = fmaxf(m_i[m][r], pm[r]);
                    resc[r] = __expf(m_i[m][r] - mn);
                    m_i[m][r] = mn;
                    l_i[m][r] *= resc[r];
                }
#pragma unroll
                for (int n = 0; n < 8; ++n)
#pragma unroll
                    for (int r = 0; r < 4; ++r)
                        acc[m][n][r] *= resc[r];
            }

            float rs[4] = {0.f, 0.f, 0.f, 0.f};
#pragma unroll
            for (int n = 0; n < 4; ++n)
#pragma unroll
                for (int r = 0; r < 4; ++r) {
                    float p = __expf(s[m][n][r] - m_i[m][r]);
                    s[m][n][r] = p;
                    rs[r] += p;
                }
#pragma unroll
            for (int o = 1; o < 16; o <<= 1)
#pragma unroll
                for (int r = 0; r < 4; ++r)
                    rs[r] += __shfl_xor(rs[r], o, 16);
#pragma unroll
            for (int r = 0; r < 4; ++r)
                l_i[m][r] += rs[r];

#pragma unroll
            for (int n = 0; n < 4; ++n)
#pragma unroll
                for (int r = 0; r < 4; ++r)
                    Pw[(m * 16 + lk * 4 + r) * 72 + n * 16 + lr] = f2bf(s[m][n][r]);
        }

        // ---- Y += P V ----
#pragma unroll
        for (int ks = 0; ks < 2; ++ks) {
            short8 pf0 = *(const short8*)&Pw[(lr) * 72 + ks * 32 + lk * 8];
            short8 pf1 = *(const short8*)&Pw[(16 + lr) * 72 + ks * 32 + lk * 8];
#pragma unroll
            for (int n8 = 0; n8 < 8; ++n8) {
                int d  = n8 * 16 + lr;
                int cb = (ks * 64 + lk * 16) ^ ((d & 7) << 4);
                short8 vf = *(const short8*)((const char*)Vt + d * 128 + cb);
                acc[0][n8] = __builtin_amdgcn_mfma_f32_16x16x32_bf16(pf0, vf, acc[0][n8], 0, 0, 0);
                acc[1][n8] = __builtin_amdgcn_mfma_f32_16x16x32_bf16(pf1, vf, acc[1][n8], 0, 0, 0);
            }
        }
        __syncthreads();

        if (pf) {
#pragma unroll
            for (int c = 0; c < 4; ++c) {
                int base = w * 4096 + c * 1024;
                *(u32x4*)((char*)Kt + base + lane * 16) = kreg[c];
                *(u32x4*)((char*)Vt + base + lane * 16) = vreg[c];
            }
        }
        __syncthreads();
    }

    unsigned short* yb = y + (size_t)(b * 1024) * 2048 + h * 128;
#pragma unroll
    for (int m = 0; m < 2; ++m)
#pragma unroll
        for (int n8 = 0; n8 < 8; ++n8)
#pragma unroll
            for (int r = 0; r < 4; ++r) {
                int t = qb0 + w * 32 + m * 16 + lk * 4 + r;
                int d = n8 * 16 + lr;
                yb[(size_t)t * 2048 + d] = f2bf(acc[m][n8][r] / l_i[m][r]);
            }
}

// ============================================================
// host launch
// ============================================================
extern "C" void kernel_launch(void* const* d_in, const int* in_sizes, int n_in,
                              void* d_out, int out_size, void* d_ws, size_t ws_size,
                              hipStream_t stream) {
    const float* v_in  = (const float*)d_in[0];
    const float* xeps  = (const float*)d_in[1];
    const float* fcos  = (const float*)d_in[2];
    const float* fsin  = (const float*)d_in[3];
    const float* Wea   = (const float*)d_in[4];
    const float* Wa    = (const float*)d_in[5];
    const float* Wp    = (const float*)d_in[6];
    const float* Wep   = (const float*)d_in[7];
    float* out = (float*)d_out;

    char* ws = (char*)d_ws;
    unsigned short* xe16 = (unsigned short*)ws;  ws += (size_t)MROWS * KDIM * 2;
    unsigned short* v16  = (unsigned short*)ws;  ws += (size_t)MROWS * KDIM * 2;
    unsigned short* WeaT = (unsigned short*)ws;  ws += (size_t)NQK * KDIM * 2;
    unsigned short* WaT  = (unsigned short*)ws;  ws += (size_t)KDIM * KDIM * 2;
    unsigned short* WpT  = (unsigned short*)ws;  ws += (size_t)KDIM * KDIM * 2;
    unsigned short* WepT = (unsigned short*)ws;  ws += (size_t)KDIM * KDIM * 2;
    unsigned short* qk16 = (unsigned short*)ws;  ws += (size_t)MROWS * NQK * 2;
    unsigned short* vpT  = (unsigned short*)ws;  ws += (size_t)MROWS * KDIM * 2;  // [64 bh][128 d][1024 t]
    unsigned short* y16  = (unsigned short*)ws;  ws += (size_t)MROWS * KDIM * 2;

    // 1. prep: casts + all 4 weight transposes, one launch
    prep_kernel<<<36864, 256, 0, stream>>>(xeps, v_in, Wea, Wa, Wp, Wep,
                                           xe16, v16, WeaT, WaT, WpT, WepT);

    // 2. merged: qk (fused RoPE, 256 blk) + vpT (mode 2, 128 blk)
    //            + x_eps_out (f32, 128 blk) = 512 blocks, one launch
    gemm256<<<512, 512, 0, stream>>>(
        xe16, WeaT, nullptr, qk16, NQK, 16, 1, 1, 256,
        v16,  WaT,  nullptr, vpT, KDIM, 8, 1, 2, 128,
        xe16, WepT, out + (size_t)MROWS * KDIM, nullptr, KDIM, 8, 0, 0,
        KDIM, KDIM, fcos, fsin);

    // 3. attention -> y16
    attn_kernel<<<dim3(64, 8), 256, 0, stream>>>(qk16, vpT, y16);

    // 4. v_out = y16 @ WpT : 128x256 tiles, 256 blocks, full K
    gemm128<<<256, 512, 0, stream>>>(y16, WpT, out, KDIM, 8, KDIM);
}

// Round 18
// 278.116 us; speedup vs baseline: 1.0448x; 1.0015x over previous
//
#include <hip/hip_runtime.h>
#include <stdint.h>

// ---------- types ----------
typedef __attribute__((ext_vector_type(8))) short  short8;   // 8 bf16 (4 VGPRs)
typedef __attribute__((ext_vector_type(4))) float  f32x4;
typedef __attribute__((ext_vector_type(4))) float  float4v;
typedef __attribute__((ext_vector_type(4))) unsigned short ushort4v;
typedef __attribute__((ext_vector_type(4))) unsigned int   u32x4;

#define DEV __device__ __forceinline__

// ---------- bf16 helpers (RNE) ----------
DEV unsigned short f2bf(float f) {
    union { float f; unsigned int u; } x; x.f = f;
    unsigned int u = x.u;
    unsigned int r = (u + 0x7fffu + ((u >> 16) & 1u)) >> 16;
    return (unsigned short)r;
}
DEV float bf2f(unsigned short b) {
    union { unsigned int u; float f; } x; x.u = ((unsigned int)b) << 16;
    return x.f;
}

// ---------- async global->LDS, 16B/lane ----------
DEV void gll16(const void* g, void* l) {
    __builtin_amdgcn_global_load_lds(
        (const __attribute__((address_space(1))) void*)g,
        (__attribute__((address_space(3))) void*)l, 16, 0, 0);
}

// ---------- problem constants ----------
#define MROWS 4096
#define KDIM  2048
#define NQK   4096

// ============================================================
// prep mega-kernel: casts (xe, v) + 4 weight transpose-casts
// ============================================================
__global__ void prep_kernel(
    const float* __restrict__ xeps, const float* __restrict__ v_in,
    const float* __restrict__ Wea, const float* __restrict__ Wa,
    const float* __restrict__ Wp,  const float* __restrict__ Wep,
    unsigned short* __restrict__ xe16, unsigned short* __restrict__ v16,
    unsigned short* __restrict__ WeaT, unsigned short* __restrict__ WaT,
    unsigned short* __restrict__ WpT,  unsigned short* __restrict__ WepT) {

    __shared__ float tile[32][33];
    const int blk = blockIdx.x, tid = threadIdx.x;

    if (blk < 16384) {   // casts
        const float* in = (blk < 8192) ? xeps : v_in;
        unsigned short* out = (blk < 8192) ? xe16 : v16;
        int i = (blk & 8191) * 256 + tid;
        float4v f = ((const float4v*)in)[i];
        ushort4v o;
        o[0] = f2bf(f[0]); o[1] = f2bf(f[1]); o[2] = f2bf(f[2]); o[3] = f2bf(f[3]);
        ((ushort4v*)out)[i] = o;
        return;
    }
    // transposes
    const float* W; unsigned short* Wt; int K, N, local;
    if (blk < 24576)      { W = Wea; Wt = WeaT; K = KDIM; N = NQK;  local = blk - 16384; }
    else if (blk < 28672) { W = Wa;  Wt = WaT;  K = KDIM; N = KDIM; local = blk - 24576; }
    else if (blk < 32768) { W = Wp;  Wt = WpT;  K = KDIM; N = KDIM; local = blk - 28672; }
    else                  { W = Wep; Wt = WepT; K = KDIM; N = KDIM; local = blk - 32768; }
    const int ntiles = N >> 5;
    const int n0 = (local % ntiles) * 32, k0 = (local / ntiles) * 32;
    const int tx = tid & 31, ty = tid >> 5;
#pragma unroll
    for (int j = 0; j < 32; j += 8)
        tile[ty + j][tx] = W[(size_t)(k0 + ty + j) * N + n0 + tx];
    __syncthreads();
#pragma unroll
    for (int j = 0; j < 32; j += 8)
        Wt[(size_t)(n0 + ty + j) * K + k0 + tx] = f2bf(tile[tx][ty + j]);
}

// ============================================================
// 256x256-tile GEMM, r6/r8 8-phase schedule; TRIPLE descriptor:
// qk(256) + vp(128) + eps(128) in one 512-block launch.
// mode: 0 = plain f32, 1 = fused RoPE (bf16), 2 = transposed vpT.
// ============================================================
__global__ __launch_bounds__(512, 2) void gemm256(
    const unsigned short* __restrict__ A0g, const unsigned short* __restrict__ B0g,
    float* __restrict__ Cf0, unsigned short* __restrict__ Ch0,
    int N0, int tx0, int outbf0, int mode0, int nb0,
    const unsigned short* __restrict__ A1g, const unsigned short* __restrict__ B1g,
    float* __restrict__ Cf1, unsigned short* __restrict__ Ch1,
    int N1, int tx1, int outbf1, int mode1, int nb1,
    const unsigned short* __restrict__ A2g, const unsigned short* __restrict__ B2g,
    float* __restrict__ Cf2, unsigned short* __restrict__ Ch2,
    int N2, int tx2, int outbf2, int mode2,
    int Kst, int Kl,
    const float* __restrict__ rC, const float* __restrict__ rS) {

    __shared__ __align__(16) char lds[131072];

    int blk = blockIdx.x;
    const unsigned short* Ag; const unsigned short* Bg;
    float* Cf; unsigned short* Ch; int N, tx, outbf, nwg, mode;
    if (blk < nb0) {
        Ag = A0g; Bg = B0g; Cf = Cf0; Ch = Ch0; N = N0; tx = tx0;
        outbf = outbf0; mode = mode0; nwg = nb0;
    } else if (blk < nb0 + nb1) {
        blk -= nb0;
        Ag = A1g; Bg = B1g; Cf = Cf1; Ch = Ch1; N = N1; tx = tx1;
        outbf = outbf1; mode = mode1; nwg = nb1;
    } else {
        blk -= nb0 + nb1;
        Ag = A2g; Bg = B2g; Cf = Cf2; Ch = Ch2; N = N2; tx = tx2;
        outbf = outbf2; mode = mode2; nwg = gridDim.x - nb0 - nb1;
    }
    // T1: XCD chunk swizzle (bijective; nwg % 8 == 0)
    { int cpx = nwg >> 3; blk = (blk & 7) * cpx + (blk >> 3); }
    const int bx = blk % tx, by = blk / tx;

    const int tid = threadIdx.x;
    const int lane = tid & 63;
    const int w  = tid >> 6;
    const int lr = lane & 15, lk = lane >> 4;
    const int wm = w >> 2, wn = w & 3;
    const int cswz16 = (lk ^ ((lr >> 3) << 1)) * 16;
    const int rdOff  = lr * 64 + cswz16;
    const int bRow0B = (wn & 1) * 4096;

    const unsigned short* Arow = Ag + (size_t)(by * 256) * Kst;
    const unsigned short* Brow = Bg + (size_t)(bx * 256) * Kst;

    const int srow = tid >> 2;
    const int sclog = (tid & 3) ^ (((tid >> 5) & 1) << 1);
    const unsigned short* aSt0 = Arow + (size_t)srow * Kst + sclog * 8;
    const unsigned short* aSt1 = aSt0 + (size_t)128 * Kst;
    const unsigned short* bSt0 = Brow + (size_t)srow * Kst + sclog * 8;
    const unsigned short* bSt1 = bSt0 + (size_t)128 * Kst;

    char* sA0 = lds;            char* sB0 = lds + 32768;
    char* sA1 = lds + 65536;    char* sB1 = lds + 98304;
    const int sOff = tid * 16;

    const char* aB0 = lds + wm * 16384;
    const char* aB1 = aB0 + 65536;
    const char* bB0 = lds + 32768 + (wn >> 1) * 16384;
    const char* bB1 = bB0 + 65536;

    f32x4 acc[8][4];
#pragma unroll
    for (int m = 0; m < 8; ++m)
#pragma unroll
        for (int n = 0; n < 4; ++n) acc[m][n] = (f32x4){0.f, 0.f, 0.f, 0.f};

    const int NT = Kl >> 6;   // even

    auto STAGE = [&](const unsigned short* srcHalf, int k0, char* ldsHalf) {
        gll16(srcHalf + k0,      ldsHalf + sOff);
        gll16(srcHalf + k0 + 32, ldsHalf + 8192 + sOff);
    };

    // ---- prologue: tile0 full (8) + A(1)h0 (2) ----
    STAGE(aSt0, 0, sA0);  STAGE(aSt1, 0, sA0 + 16384);
    STAGE(bSt0, 0, sB0);  STAGE(bSt1, 0, sB0 + 16384);
    STAGE(aSt0, 64, sA1);
    asm volatile("s_waitcnt vmcnt(2)" ::: "memory");
    __builtin_amdgcn_s_barrier();

#define MFMA_BF(a, b, c) __builtin_amdgcn_mfma_f32_16x16x32_bf16(a, b, c, 0, 0, 0)

#define RD_A(BASE, MH)                                                               \
    _Pragma("unroll") for (int i = 0; i < 4; ++i) {                                  \
        Ar[i][0] = *(const short8*)((BASE) +        (MH) * 4096 + i * 1024 + rdOff); \
        Ar[i][1] = *(const short8*)((BASE) + 8192 + (MH) * 4096 + i * 1024 + rdOff); \
    }

#define RD_B(BASE, NH)                                                                        \
    _Pragma("unroll") for (int j = 0; j < 2; ++j) {                                           \
        Br[j][0] = *(const short8*)((BASE) +        bRow0B + ((NH) * 2 + j) * 1024 + rdOff);  \
        Br[j][1] = *(const short8*)((BASE) + 8192 + bRow0B + ((NH) * 2 + j) * 1024 + rdOff);  \
    }

#define MFMA16(MH, NH)                                                       \
    __builtin_amdgcn_s_setprio(1);                                           \
    _Pragma("unroll") for (int ks = 0; ks < 2; ++ks)                         \
        _Pragma("unroll") for (int i = 0; i < 4; ++i)                        \
            _Pragma("unroll") for (int j = 0; j < 2; ++j)                    \
                acc[(MH) * 4 + i][(NH) * 2 + j] =                            \
                    MFMA_BF(Ar[i][ks], Br[j][ks], acc[(MH) * 4 + i][(NH) * 2 + j]); \
    __builtin_amdgcn_s_setprio(0);

#define PH(RDS, STG, MFMAQ, VMW)                               \
    {                                                          \
        RDS;                                                   \
        STG;                                                   \
        __builtin_amdgcn_s_barrier();                          \
        asm volatile("s_waitcnt lgkmcnt(0)" ::: "memory");     \
        __builtin_amdgcn_sched_barrier(0);                     \
        MFMAQ;                                                 \
        VMW;                                                   \
        __builtin_amdgcn_s_barrier();                          \
    }

#define VMC2 asm volatile("s_waitcnt vmcnt(2)" ::: "memory")

    short8 Ar[4][2], Br[2][2];

    for (int i2 = 0; i2 < NT; i2 += 2) {
        const int kt1 = (i2 + 1) * 64;
        const int kA  = (i2 + 2 < NT ? i2 + 2 : NT - 1) * 64;
        const int kA3 = (i2 + 3 < NT ? i2 + 3 : NT - 1) * 64;

        // ---- K-tile t0 (buf0) ----
        PH({ RD_A(aB0, 0) RD_B(bB0, 0) },
           { STAGE(aSt1, kt1, sA1 + 16384); STAGE(bSt0, kt1, sB1); STAGE(bSt1, kt1, sB1 + 16384); },
           MFMA16(0, 0), {})
        PH({ RD_B(bB0, 1) }, {}, MFMA16(0, 1), {})
        PH({ RD_A(aB0, 1) RD_B(bB0, 0) }, {}, MFMA16(1, 0), {})
        PH({ RD_B(bB0, 1) },
           { STAGE(aSt0, kA, sA0); },
           MFMA16(1, 1), VMC2)

        // ---- K-tile t1 (buf1) ----
        PH({ RD_A(aB1, 0) RD_B(bB1, 0) },
           { STAGE(aSt1, kA, sA0 + 16384); STAGE(bSt0, kA, sB0); STAGE(bSt1, kA, sB0 + 16384); },
           MFMA16(0, 0), {})
        PH({ RD_B(bB1, 1) }, {}, MFMA16(0, 1), {})
        PH({ RD_A(aB1, 1) RD_B(bB1, 0) }, {}, MFMA16(1, 0), {})
        PH({ RD_B(bB1, 1) },
           { STAGE(aSt0, kA3, sA1); },
           MFMA16(1, 1), VMC2)
    }
    asm volatile("s_waitcnt vmcnt(0)" ::: "memory");
#undef RD_A
#undef RD_B
#undef MFMA16
#undef PH
#undef VMC2

    // ---- epilogue: C/D layout col = lane&15, row = (lane>>4)*4 + reg ----
    if (outbf) {
        if (mode == 1) {
#pragma unroll
            for (int mf = 0; mf < 8; ++mf)
#pragma unroll
                for (int nf = 0; nf < 4; ++nf)
#pragma unroll
                    for (int r = 0; r < 4; ++r) {
                        int row = by * 256 + wm * 128 + mf * 16 + lk * 4 + r;
                        int col = bx * 256 + wn * 64 + nf * 16 + lr;
                        float val = acc[mf][nf][r];
                        float part = __shfl_xor(val, 1);
                        int t = row & 1023;
                        int i = (col & 127) >> 1;
                        float c = rC[t * 64 + i];
                        float s = rS[t * 64 + i];
                        float o = (lr & 1) ? (part * s + val * c)
                                           : (val * c - part * s);
                        Ch[(size_t)row * N + col] = f2bf(o);
                    }
        } else if (mode == 2) {
            // transposed vpT write: one 8B store per (mf,nf)
#pragma unroll
            for (int mf = 0; mf < 8; ++mf)
#pragma unroll
                for (int nf = 0; nf < 4; ++nf) {
                    int row0 = by * 256 + wm * 128 + mf * 16 + lk * 4;   // r = 0
                    int col  = bx * 256 + wn * 64 + nf * 16 + lr;
                    int b = row0 >> 10, t0 = row0 & 1023;
                    int h = col >> 7,  d  = col & 127;
                    ushort4v o;
#pragma unroll
                    for (int r = 0; r < 4; ++r) o[r] = f2bf(acc[mf][nf][r]);
                    *(ushort4v*)(Ch + (size_t)(b * 16 + h) * 131072
                                    + (size_t)d * 1024 + t0) = o;
                }
        } else {
#pragma unroll
            for (int mf = 0; mf < 8; ++mf)
#pragma unroll
                for (int nf = 0; nf < 4; ++nf)
#pragma unroll
                    for (int r = 0; r < 4; ++r) {
                        int row = by * 256 + wm * 128 + mf * 16 + lk * 4 + r;
                        int col = bx * 256 + wn * 64 + nf * 16 + lr;
                        Ch[(size_t)row * N + col] = f2bf(acc[mf][nf][r]);
                    }
        }
    } else {
#pragma unroll
        for (int mf = 0; mf < 8; ++mf)
#pragma unroll
            for (int nf = 0; nf < 4; ++nf)
#pragma unroll
                for (int r = 0; r < 4; ++r) {
                    int row = by * 256 + wm * 128 + mf * 16 + lk * 4 + r;
                    int col = bx * 256 + wn * 64 + nf * 16 + lr;
                    Cf[(size_t)row * N + col] = acc[mf][nf][r];
                }
    }
}

// ============================================================
// 128x256-tile GEMM (proj): 32x8 = 256 blocks, no K-split/add.
// ============================================================
__global__ __launch_bounds__(512) void gemm128(
    const unsigned short* __restrict__ Ag, const unsigned short* __restrict__ Bg,
    float* __restrict__ Cf, int N, int tx, int Kst) {

    __shared__ __align__(16) char lds[98304];

    int blk = blockIdx.x;
    { int cpx = (int)gridDim.x >> 3; blk = (blk & 7) * cpx + (blk >> 3); }   // T1
    const int bx = blk % tx, by = blk / tx;

    const int tid = threadIdx.x;
    const int lane = tid & 63;
    const int w  = tid >> 6;
    const int lr = lane & 15, lk = lane >> 4;
    const int wm = w >> 2, wn = w & 3;
    const int cswz16 = (lk ^ ((lr >> 3) << 1)) * 16;
    const int rdOff  = lr * 64 + cswz16;
    const int bRow0B = (wn & 1) * 4096;

    const unsigned short* Arow = Ag + (size_t)(by * 128) * Kst;
    const unsigned short* Brow = Bg + (size_t)(bx * 256) * Kst;

    const int srow = tid >> 2;
    const int sclog = (tid & 3) ^ (((tid >> 5) & 1) << 1);
    const unsigned short* aSt  = Arow + (size_t)srow * Kst + sclog * 8;
    const unsigned short* bSt0 = Brow + (size_t)srow * Kst + sclog * 8;
    const unsigned short* bSt1 = bSt0 + (size_t)128 * Kst;

    const int sOff = tid * 16;

    f32x4 acc[4][4];
#pragma unroll
    for (int m = 0; m < 4; ++m)
#pragma unroll
        for (int n = 0; n < 4; ++n) acc[m][n] = (f32x4){0.f, 0.f, 0.f, 0.f};

    const int NT = Kst >> 6;

    auto STAGE = [&](const unsigned short* srcHalf, int k0, char* ldsHalf) {
        gll16(srcHalf + k0,      ldsHalf + sOff);
        gll16(srcHalf + k0 + 32, ldsHalf + 8192 + sOff);
    };

#define MFMA_BF(a, b, c) __builtin_amdgcn_mfma_f32_16x16x32_bf16(a, b, c, 0, 0, 0)

    // ---- prologue: A(0), B(0), A(1) ----
    STAGE(aSt,  0,  lds);
    STAGE(bSt0, 0,  lds + 16384);  STAGE(bSt1, 0, lds + 32768);
    STAGE(aSt,  64, lds + 49152);
    asm volatile("s_waitcnt vmcnt(2)" ::: "memory");
    __builtin_amdgcn_s_barrier();

    short8 Ar[4][2], Br[2][2];

    for (int t = 0; t < NT; ++t) {
        const int par = t & 1;
        const char* aW = lds + (par ? 49152 : 0) + wm * 4096;
        const char* bC = lds + (par ? 65536 : 16384) + (wn >> 1) * 16384;
        char* dB = lds + (par ? 16384 : 65536);
        char* dA = lds + (par ? 49152 : 0);
        const int kB  = (t + 1 < NT ? t + 1 : NT - 1) * 64;
        const int kA2 = (t + 2 < NT ? t + 2 : NT - 1) * 64;

        // ---- ph0: read A(all) + B nf0-1 ; stage B(t+1) ----
#pragma unroll
        for (int i = 0; i < 4; ++i) {
            Ar[i][0] = *(const short8*)(aW +        i * 1024 + rdOff);
            Ar[i][1] = *(const short8*)(aW + 8192 + i * 1024 + rdOff);
        }
#pragma unroll
        for (int j = 0; j < 2; ++j) {
            Br[j][0] = *(const short8*)(bC +        bRow0B + j * 1024 + rdOff);
            Br[j][1] = *(const short8*)(bC + 8192 + bRow0B + j * 1024 + rdOff);
        }
        STAGE(bSt0, kB, dB);  STAGE(bSt1, kB, dB + 16384);
        __builtin_amdgcn_s_barrier();
        asm volatile("s_waitcnt lgkmcnt(0)" ::: "memory");
        __builtin_amdgcn_sched_barrier(0);
        __builtin_amdgcn_s_setprio(1);
#pragma unroll
        for (int ks = 0; ks < 2; ++ks)
#pragma unroll
            for (int i = 0; i < 4; ++i)
#pragma unroll
                for (int j = 0; j < 2; ++j)
                    acc[i][j] = MFMA_BF(Ar[i][ks], Br[j][ks], acc[i][j]);
        __builtin_amdgcn_s_setprio(0);
        __builtin_amdgcn_s_barrier();

        // ---- ph1: read B nf2-3 ; stage A(t+2) ----
#pragma unroll
        for (int j = 0; j < 2; ++j) {
            Br[j][0] = *(const short8*)(bC +        bRow0B + (2 + j) * 1024 + rdOff);
            Br[j][1] = *(const short8*)(bC + 8192 + bRow0B + (2 + j) * 1024 + rdOff);
        }
        STAGE(aSt, kA2, dA);
        __builtin_amdgcn_s_barrier();
        asm volatile("s_waitcnt lgkmcnt(0)" ::: "memory");
        __builtin_amdgcn_sched_barrier(0);
        __builtin_amdgcn_s_setprio(1);
#pragma unroll
        for (int ks = 0; ks < 2; ++ks)
#pragma unroll
            for (int i = 0; i < 4; ++i)
#pragma unroll
                for (int j = 0; j < 2; ++j)
                    acc[i][2 + j] = MFMA_BF(Ar[i][ks], Br[j][ks], acc[i][2 + j]);
        __builtin_amdgcn_s_setprio(0);
        asm volatile("s_waitcnt vmcnt(2)" ::: "memory");
        __builtin_amdgcn_s_barrier();
    }
    asm volatile("s_waitcnt vmcnt(0)" ::: "memory");
#undef MFMA_BF

    // ---- epilogue: f32 ----
#pragma unroll
    for (int mf = 0; mf < 4; ++mf)
#pragma unroll
        for (int nf = 0; nf < 4; ++nf)
#pragma unroll
            for (int r = 0; r < 4; ++r) {
                int row = by * 128 + wm * 64 + mf * 16 + lk * 4 + r;
                int col = bx * 256 + wn * 64 + nf * 16 + lr;
                Cf[(size_t)row * N + col] = acc[mf][nf][r];
            }
}

// ============================================================
// Flash-style causal attention:
// T14 async-stage split + T13 defer-max (THR=8).
// qt = 7 - blockIdx.y: heavy tiles dispatch FIRST (LPT order --
// r16 showed ascending second-half order costs +12us).
// ============================================================
__global__ __launch_bounds__(256) void attn_kernel(
    const unsigned short* __restrict__ qk,
    const unsigned short* __restrict__ vpT,
    unsigned short* __restrict__ y) {

    const int bh = blockIdx.x;
    const int qt = 7 - (int)blockIdx.y;
    const int b = bh >> 4, h = bh & 15;
    const int qb0 = qt * 128;

    __shared__ __align__(16) unsigned short Kt[64 * 128];
    __shared__ __align__(16) unsigned short Vt[128 * 64];
    __shared__ __align__(16) unsigned short Pl[4 * 32 * 72];

    const int tid = threadIdx.x, w = tid >> 6, lane = tid & 63;
    const int lr = lane & 15, lk = lane >> 4;

    const unsigned short* Qb = qk + (size_t)(b * 1024) * 4096 + h * 128;
    const unsigned short* Kb = Qb + 2048;
    const unsigned short* Vg = vpT + (size_t)bh * 128 * 1024;
    unsigned short* Pw = &Pl[w * 32 * 72];

    short8 qf[2][4];
#pragma unroll
    for (int m = 0; m < 2; ++m) {
        const unsigned short* qrow = Qb + (size_t)(qb0 + w * 32 + m * 16 + lr) * 4096;
#pragma unroll
        for (int db = 0; db < 4; ++db)
            qf[m][db] = *(const short8*)(qrow + db * 32 + lk * 8);
    }

    f32x4 acc[2][8];
#pragma unroll
    for (int m = 0; m < 2; ++m)
#pragma unroll
        for (int n = 0; n < 8; ++n) acc[m][n] = (f32x4){0.f, 0.f, 0.f, 0.f};
    float m_i[2][4], l_i[2][4];
#pragma unroll
    for (int m = 0; m < 2; ++m)
#pragma unroll
        for (int r = 0; r < 4; ++r) { m_i[m][r] = -1e30f; l_i[m][r] = 0.f; }

    const int nkt = 2 * qt + 2;

    // ---- prologue: stage tile 0 via global_load_lds ----
#pragma unroll
    for (int c = 0; c < 4; ++c) {
        int base = w * 4096 + c * 1024;
        int row  = (base >> 8) + (lane >> 4);
        int scol = ((lane & 15) * 16) ^ ((row & 7) << 4);
        gll16(Kb + (size_t)row * 4096 + (scol >> 1), (char*)Kt + base);
        int d    = (base >> 7) + (lane >> 3);
        int svol = ((lane & 7) * 16) ^ ((d & 7) << 4);
        gll16(Vg + (size_t)d * 1024 + (svol >> 1), (char*)Vt + base);
    }
    __syncthreads();

    u32x4 kreg[4], vreg[4];

    for (int kt = 0; kt < nkt; ++kt) {
        const bool pf = (kt + 1 < nkt);
        if (pf) {
            const int ktn = kt + 1;
#pragma unroll
            for (int c = 0; c < 4; ++c) {
                int base = w * 4096 + c * 1024;
                int row  = (base >> 8) + (lane >> 4);
                int scol = ((lane & 15) * 16) ^ ((row & 7) << 4);
                kreg[c] = *(const u32x4*)(Kb + (size_t)(ktn * 64 + row) * 4096 + (scol >> 1));
                int d    = (base >> 7) + (lane >> 3);
                int svol = ((lane & 7) * 16) ^ ((d & 7) << 4);
                vreg[c] = *(const u32x4*)(Vg + (size_t)d * 1024 + ktn * 64 + (svol >> 1));
            }
        }

        // ---- S = Q K^T ----
        f32x4 s[2][4];
#pragma unroll
        for (int m = 0; m < 2; ++m)
#pragma unroll
            for (int n = 0; n < 4; ++n) s[m][n] = (f32x4){0.f, 0.f, 0.f, 0.f};
#pragma unroll
        for (int db = 0; db < 4; ++db)
#pragma unroll
            for (int n = 0; n < 4; ++n) {
                int krow = n * 16 + lr;
                int cb = (db * 64 + lk * 16) ^ ((krow & 7) << 4);
                short8 kf = *(const short8*)((const char*)Kt + krow * 256 + cb);
                s[0][n] = __builtin_amdgcn_mfma_f32_16x16x32_bf16(qf[0][db], kf, s[0][n], 0, 0, 0);
                s[1][n] = __builtin_amdgcn_mfma_f32_16x16x32_bf16(qf[1][db], kf, s[1][n], 0, 0, 0);
            }

        const float sc = 0.08838834764831845f;
        const bool diag = (kt >= 2 * qt);
#pragma unroll
        for (int m = 0; m < 2; ++m)
#pragma unroll
            for (int n = 0; n < 4; ++n)
#pragma unroll
                for (int r = 0; r < 4; ++r) {
                    float v = s[m][n][r] * sc;
                    if (diag) {
                        int q   = qb0 + w * 32 + m * 16 + lk * 4 + r;
                        int key = kt * 64 + n * 16 + lr;
                        if (key > q) v = -1e30f;
                    }
                    s[m][n][r] = v;
                }

        // ---- online softmax with defer-max (T13, THR=8) ----
#pragma unroll
        for (int m = 0; m < 2; ++m) {
            float pm[4];
#pragma unroll
            for (int r = 0; r < 4; ++r)
                pm[r] = fmaxf(fmaxf(s[m][0][r], s[m][1][r]), fmaxf(s[m][2][r], s[m][3][r]));
#pragma unroll
            for (int o = 1; o < 16; o <<= 1)
#pragma unroll
                for (int r = 0; r < 4; ++r)
                    pm[r] = fmaxf(pm[r], __shfl_xor(pm[r], o, 16));

            bool small = true;
#pragma unroll
            for (int r = 0; r < 4; ++r)
                small = small && (pm[r] <= m_i[m][r] + 8.0f);
            if (!__all((int)small)) {
                float resc[4];
#pragma unroll
                for (int r = 0; r < 4; ++r) {
                    float mn = fmaxf(m_i[m][r], pm[r]);
                    resc[r] = __expf(m_i[m][r] - mn);
                    m_i[m][r] = mn;
                    l_i[m][r] *= resc[r];
                }
#pragma unroll
                for (int n = 0; n < 8; ++n)
#pragma unroll
                    for (int r = 0; r < 4; ++r)
                        acc[m][n][r] *= resc[r];
            }

            float rs[4] = {0.f, 0.f, 0.f, 0.f};
#pragma unroll
            for (int n = 0; n < 4; ++n)
#pragma unroll
                for (int r = 0; r < 4; ++r) {
                    float p = __expf(s[m][n][r] - m_i[m][r]);
                    s[m][n][r] = p;
                    rs[r] += p;
                }
#pragma unroll
            for (int o = 1; o < 16; o <<= 1)
#pragma unroll
                for (int r = 0; r < 4; ++r)
                    rs[r] += __shfl_xor(rs[r], o, 16);
#pragma unroll
            for (int r = 0; r < 4; ++r)
                l_i[m][r] += rs[r];

#pragma unroll
            for (int n = 0; n < 4; ++n)
#pragma unroll
                for (int r = 0; r < 4; ++r)
                    Pw[(m * 16 + lk * 4 + r) * 72 + n * 16 + lr] = f2bf(s[m][n][r]);
        }

        // ---- Y += P V ----
#pragma unroll
        for (int ks = 0; ks < 2; ++ks) {
            short8 pf0 = *(const short8*)&Pw[(lr) * 72 + ks * 32 + lk * 8];
            short8 pf1 = *(const short8*)&Pw[(16 + lr) * 72 + ks * 32 + lk * 8];
#pragma unroll
            for (int n8 = 0; n8 < 8; ++n8) {
                int d  = n8 * 16 + lr;
                int cb = (ks * 64 + lk * 16) ^ ((d & 7) << 4);
                short8 vf = *(const short8*)((const char*)Vt + d * 128 + cb);
                acc[0][n8] = __builtin_amdgcn_mfma_f32_16x16x32_bf16(pf0, vf, acc[0][n8], 0, 0, 0);
                acc[1][n8] = __builtin_amdgcn_mfma_f32_16x16x32_bf16(pf1, vf, acc[1][n8], 0, 0, 0);
            }
        }
        __syncthreads();

        if (pf) {
#pragma unroll
            for (int c = 0; c < 4; ++c) {
                int base = w * 4096 + c * 1024;
                *(u32x4*)((char*)Kt + base + lane * 16) = kreg[c];
                *(u32x4*)((char*)Vt + base + lane * 16) = vreg[c];
            }
        }
        __syncthreads();
    }

    unsigned short* yb = y + (size_t)(b * 1024) * 2048 + h * 128;
#pragma unroll
    for (int m = 0; m < 2; ++m)
#pragma unroll
        for (int n8 = 0; n8 < 8; ++n8)
#pragma unroll
            for (int r = 0; r < 4; ++r) {
                int t = qb0 + w * 32 + m * 16 + lk * 4 + r;
                int d = n8 * 16 + lr;
                yb[(size_t)t * 2048 + d] = f2bf(acc[m][n8][r] / l_i[m][r]);
            }
}

// ============================================================
// host launch
// ============================================================
extern "C" void kernel_launch(void* const* d_in, const int* in_sizes, int n_in,
                              void* d_out, int out_size, void* d_ws, size_t ws_size,
                              hipStream_t stream) {
    const float* v_in  = (const float*)d_in[0];
    const float* xeps  = (const float*)d_in[1];
    const float* fcos  = (const float*)d_in[2];
    const float* fsin  = (const float*)d_in[3];
    const float* Wea   = (const float*)d_in[4];
    const float* Wa    = (const float*)d_in[5];
    const float* Wp    = (const float*)d_in[6];
    const float* Wep   = (const float*)d_in[7];
    float* out = (float*)d_out;

    char* ws = (char*)d_ws;
    unsigned short* xe16 = (unsigned short*)ws;  ws += (size_t)MROWS * KDIM * 2;
    unsigned short* v16  = (unsigned short*)ws;  ws += (size_t)MROWS * KDIM * 2;
    unsigned short* WeaT = (unsigned short*)ws;  ws += (size_t)NQK * KDIM * 2;
    unsigned short* WaT  = (unsigned short*)ws;  ws += (size_t)KDIM * KDIM * 2;
    unsigned short* WpT  = (unsigned short*)ws;  ws += (size_t)KDIM * KDIM * 2;
    unsigned short* WepT = (unsigned short*)ws;  ws += (size_t)KDIM * KDIM * 2;
    unsigned short* qk16 = (unsigned short*)ws;  ws += (size_t)MROWS * NQK * 2;
    unsigned short* vpT  = (unsigned short*)ws;  ws += (size_t)MROWS * KDIM * 2;  // [64 bh][128 d][1024 t]
    unsigned short* y16  = (unsigned short*)ws;  ws += (size_t)MROWS * KDIM * 2;

    // 1. prep: casts + all 4 weight transposes, one launch
    prep_kernel<<<36864, 256, 0, stream>>>(xeps, v_in, Wea, Wa, Wp, Wep,
                                           xe16, v16, WeaT, WaT, WpT, WepT);

    // 2. merged: qk (fused RoPE, 256 blk) + vpT (mode 2, 128 blk)
    //            + x_eps_out (f32, 128 blk) = 512 blocks, one launch
    gemm256<<<512, 512, 0, stream>>>(
        xe16, WeaT, nullptr, qk16, NQK, 16, 1, 1, 256,
        v16,  WaT,  nullptr, vpT, KDIM, 8, 1, 2, 128,
        xe16, WepT, out + (size_t)MROWS * KDIM, nullptr, KDIM, 8, 0, 0,
        KDIM, KDIM, fcos, fsin);

    // 3. attention -> y16
    attn_kernel<<<dim3(64, 8), 256, 0, stream>>>(qk16, vpT, y16);

    // 4. v_out = y16 @ WpT : 128x256 tiles, 256 blocks, full K
    gemm128<<<256, 512, 0, stream>>>(y16, WpT, out, KDIM, 8, KDIM);
}